// Round 1
// baseline (443.603 us; speedup 1.0000x reference)
//
#include <hip/hip_runtime.h>
#include <hip/hip_bf16.h>

typedef _Float16 half8 __attribute__((ext_vector_type(8)));
typedef _Float16 half2_t __attribute__((ext_vector_type(2)));
typedef float f32x4 __attribute__((ext_vector_type(4)));

#define B_SZ 64
#define T_SZ 512
#define E_SZ 768
#define H_SZ 256
#define V_SZ 3072

// workspace layout (bytes)
#define WS_X     0u          // _Float16 x[T][B][H]           16,777,216 B
#define WS_WT    16777216u   // _Float16 Wt[256][768] (Wxh^T)    393,216 B
#define WS_WF    17170432u   // (unused now; kept so WS_H offset is stable)
#define WS_H     17301504u   // float    h[64][256]               65,536 B

// fast tanh: 1 - 2/(1+exp(2x)); exact at +/-inf, ~1e-6 rel err
static __device__ __forceinline__ float fast_tanh(float x) {
  float e = __builtin_amdgcn_exp2f(x * 2.8853900817779268f); // exp(2x)
  return 1.0f - 2.0f * __builtin_amdgcn_rcpf(1.0f + e);
}

// v_dot2_f32_f16: c += h2.x*w2.x + h2.y*w2.y  (f32 accumulate, f16 inputs)
static __device__ __forceinline__ float dot2(unsigned int h2, unsigned int w2, float c) {
  return __builtin_amdgcn_fdot2(__builtin_bit_cast(half2_t, h2),
                                __builtin_bit_cast(half2_t, w2), c, false);
}

// ---------------- k0: prep f16 Wt layout for k1 (small) ----------------
// Wt[h][e] = Wxh[e][h] (k1 B panels).
__global__ __launch_bounds__(256) void k0_convert(
    const float* __restrict__ Wxh,
    _Float16* __restrict__ Wt)
{
  int gid = blockIdx.x * 256 + threadIdx.x;           // 768 WGs = 196608
  if (gid < E_SZ * H_SZ) {
    int e = gid >> 8, h = gid & 255;
    Wt[h * E_SZ + e] = (_Float16)Wxh[gid];
  }
}

// ---------------- k1: x[t,b,:] = emb[idx[b,t],:] @ Wxh  (MFMA f16) ----------------
// Double-buffered B panel: ONE barrier per ki (was two).
__global__ __launch_bounds__(256) void k1_xproj(
    const int* __restrict__ idx,
    const float* __restrict__ emb,
    const _Float16* __restrict__ Wt,
    _Float16* __restrict__ x)
{
  const int tid  = threadIdx.x;
  const int w    = tid >> 6;
  const int lane = tid & 63;
  const int m16  = lane & 15;
  const int quad = lane >> 4;
  const int r = blockIdx.x * 64 + w * 16 + m16;     // row in [T*B], r = t*64 + b
  const int t = r >> 6;
  const int b = r & 63;
  const int erow = idx[b * T_SZ + t];
  const float* Arow = emb + (size_t)erow * E_SZ + quad * 8;   // A[m][k=quad*8+j]

  __shared__ __align__(16) _Float16 bp[2][16 * 64 * 8]; // 2 x 16KB fragment panels
  int n_[4], kb_[4];
#pragma unroll
  for (int pp = 0; pp < 4; ++pp) {
    int f = tid + 256 * pp;
    n_[pp]  = ((f >> 6) << 4) | (f & 15);
    kb_[pp] = (f >> 4) & 3;
  }
  uint4 stg[4];
#pragma unroll
  for (int pp = 0; pp < 4; ++pp)
    stg[pp] = *(const uint4*)(Wt + (size_t)n_[pp] * E_SZ + kb_[pp] * 8);
  f32x4 af0 = *(const f32x4*)(Arow);
  f32x4 af1 = *(const f32x4*)(Arow + 4);

  f32x4 acc[16];
#pragma unroll
  for (int n = 0; n < 16; ++n) { f32x4 z = {0.f, 0.f, 0.f, 0.f}; acc[n] = z; }

  // stage panel 0
#pragma unroll
  for (int pp = 0; pp < 4; ++pp)
    *(uint4*)(bp[0] + (size_t)(tid + 256 * pp) * 8) = stg[pp];
  __syncthreads();

#pragma unroll 1
  for (int ki = 0; ki < 24; ++ki) {
    const _Float16* cur = bp[ki & 1];
    f32x4 af0n = af0, af1n = af1;
    if (ki < 23) {                            // prefetch next panel + next A
#pragma unroll
      for (int pp = 0; pp < 4; ++pp)
        stg[pp] = *(const uint4*)(Wt + (size_t)n_[pp] * E_SZ + (ki + 1) * 32 + kb_[pp] * 8);
      af0n = *(const f32x4*)(Arow + (ki + 1) * 32);
      af1n = *(const f32x4*)(Arow + (ki + 1) * 32 + 4);
    }
    half8 a;
#pragma unroll
    for (int e = 0; e < 4; ++e) { a[e] = (_Float16)af0[e]; a[4 + e] = (_Float16)af1[e]; }
#pragma unroll
    for (int nt = 0; nt < 16; ++nt) {
      half8 bb = *(const half8*)(cur + (size_t)(nt * 64 + lane) * 8);
      acc[nt] = __builtin_amdgcn_mfma_f32_16x16x32_f16(a, bb, acc[nt], 0, 0, 0);
    }
    if (ki < 23) {                            // write next buffer, one barrier
#pragma unroll
      for (int pp = 0; pp < 4; ++pp)
        *(uint4*)(bp[(ki + 1) & 1] + (size_t)(tid + 256 * pp) * 8) = stg[pp];
      __syncthreads();
    }
    af0 = af0n; af1 = af1n;
  }
  const int rbase = blockIdx.x * 64 + w * 16 + quad * 4;  // C/D: col=lane&15, row=quad*4+reg
#pragma unroll
  for (int nt = 0; nt < 16; ++nt) {
    const int col = nt * 16 + m16;
#pragma unroll
    for (int rg = 0; rg < 4; ++rg) {
      x[(size_t)(rbase + rg) * H_SZ + col] = (_Float16)acc[nt][rg];
    }
  }
}

// ---------------- k2: VALU-dot2 recurrence ----------------
// Replicated-A MFMA wasted 15/16 of the matrix pipe (505 cyc/step of pipe for
// 65536 useful MACs = 26 MAC/cyc/SIMD). v_dot2_f32_f16 does 64 useful
// MAC/cyc/SIMD: thread tid owns output column tid, Whh column lives in 128
// packed-f16 VGPRs for the whole kernel, h broadcast via wave-uniform LDS
// b128 reads (conflict-free). 4 independent f32 accumulators pipeline the
// VALU (dep distance 4 instrs > 4-cy FMA latency). Time loop unrolled x2 so
// the x[t] prefetch gets a true 2-step (~1000 cy) distance with no
// rotation-copy vmcnt stall.
__global__ __launch_bounds__(256, 1) void k2_rnn(
    const float* __restrict__ Whh,
    const _Float16* __restrict__ x,
    const float* __restrict__ Bh,
    float* __restrict__ hout,
    float* __restrict__ hidout)
{
  const int b   = blockIdx.x;
  const int tid = threadIdx.x;
  __shared__ __align__(16) _Float16 hb[2][H_SZ];   // h as f16, double-buffered

  // W column tid, packed f16 pairs: wc[p] = (Whh[2p][tid], Whh[2p+1][tid])
  unsigned int wc[128];
#pragma unroll
  for (int p = 0; p < 128; ++p) {
    _Float16 w0 = (_Float16)Whh[(size_t)(2 * p)     * H_SZ + tid];
    _Float16 w1 = (_Float16)Whh[(size_t)(2 * p + 1) * H_SZ + tid];
    half2_t pk; pk[0] = w0; pk[1] = w1;
    wc[p] = __builtin_bit_cast(unsigned int, pk);
  }

  const float bhj = Bh[tid];
  const _Float16* xp = x + b * H_SZ + tid;
  _Float16 xA = xp[0];                               // for t=0
  _Float16 xB = xp[(size_t)(B_SZ * H_SZ)];           // for t=1
  hb[1][tid] = (_Float16)0.f;                        // t=0 reads buffer 1 = zeros
  float hval = 0.f;
  __syncthreads();

#define RNN_STEP(HR, HW, XF)                                           \
  {                                                                    \
    const uint4* hq4 = (const uint4*)(HR);                             \
    float a0 = 0.f, a1 = 0.f, a2 = 0.f, a3 = 0.f;                      \
    _Pragma("unroll")                                                  \
    for (int kk = 0; kk < 32; ++kk) {                                  \
      uint4 hq = hq4[kk];                                              \
      a0 = dot2(hq.x, wc[4 * kk + 0], a0);                             \
      a1 = dot2(hq.y, wc[4 * kk + 1], a1);                             \
      a2 = dot2(hq.z, wc[4 * kk + 2], a2);                             \
      a3 = dot2(hq.w, wc[4 * kk + 3], a3);                             \
    }                                                                  \
    float y = (a0 + a1) + (a2 + a3);                                   \
    hval = fast_tanh(y + (XF));                                        \
    (HW)[tid] = (_Float16)hval;                                        \
    __syncthreads();                                                   \
  }

#pragma unroll 1
  for (int tt = 0; tt < 256; ++tt) {
    // ---- step A: t = 2tt, read hb[1], write hb[0]
    float xfA = (float)xA + bhj;        // waits on load issued 2 steps ago
    int ta = 2 * tt + 2; ta = ta > 511 ? 511 : ta;
    xA = xp[(size_t)ta * (B_SZ * H_SZ)];   // reload same reg: next wait is 2 steps out
    RNN_STEP(hb[1], hb[0], xfA)
    // ---- step B: t = 2tt+1, read hb[0], write hb[1]
    float xfB = (float)xB + bhj;
    int tb = 2 * tt + 3; tb = tb > 511 ? 511 : tb;
    xB = xp[(size_t)tb * (B_SZ * H_SZ)];
    RNN_STEP(hb[0], hb[1], xfB)
  }
#undef RNN_STEP
  hout[b * H_SZ + tid] = hval;
  hidout[b * H_SZ + tid] = hval;
}

// ---------------- k3: out = hidden @ Wy + By  (all f32) ----------------
__global__ __launch_bounds__(256) void k3_out(
    const float* __restrict__ h,
    const float* __restrict__ Wy,
    const float* __restrict__ By,
    float* __restrict__ out)
{
  __shared__ float hs[H_SZ];
  const int c = blockIdx.x;   // vocab chunk
  const int b = blockIdx.y;   // batch
  const int v = c * 256 + threadIdx.x;
  hs[threadIdx.x] = h[b * H_SZ + threadIdx.x];
  __syncthreads();
  float acc = By[v];
#pragma unroll 8
  for (int jj = 0; jj < H_SZ; ++jj) {
    acc += hs[jj] * Wy[(size_t)jj * V_SZ + v];
  }
  out[(size_t)b * V_SZ + v] = acc;
}

extern "C" void kernel_launch(void* const* d_in, const int* in_sizes, int n_in,
                              void* d_out, int out_size, void* d_ws, size_t ws_size,
                              hipStream_t stream)
{
  const int*   idx = (const int*)d_in[0];
  const float* emb = (const float*)d_in[1];
  const float* Wxh = (const float*)d_in[2];
  const float* Whh = (const float*)d_in[3];
  const float* Wy  = (const float*)d_in[4];
  const float* By  = (const float*)d_in[5];
  const float* Bh  = (const float*)d_in[6];

  char* ws = (char*)d_ws;
  _Float16* x    = (_Float16*)(ws + WS_X);
  _Float16* Wt   = (_Float16*)(ws + WS_WT);
  float*    hbuf = (float*)(ws + WS_H);

  float* out    = (float*)d_out;
  float* hidout = out + (size_t)B_SZ * V_SZ;

  k0_convert<<<768, 256, 0, stream>>>(Wxh, Wt);
  k1_xproj  <<<512, 256, 0, stream>>>(idx, emb, Wt, x);
  k2_rnn    <<<64, 256, 0, stream>>>(Whh, x, Bh, hbuf, hidout);
  k3_out    <<<dim3(12, 64), 256, 0, stream>>>(hbuf, Wy, By, out);
}